// Round 4
// baseline (274.382 us; speedup 1.0000x reference)
//
#include <hip/hip_runtime.h>

// Focal loss (gamma=2, w0=w1=1) mean over N=2^25: -mean(log(s)*(1-s)^2),
// s = t ? p : 1-p. Two-stage reduction (no atomics).
//
// R6 post-mortem: grid-stride +4% only -> access pattern NULL. Across R2/
// R4/R5/R6 (VGPR 16-68, occ 23-71%) delivered BW pinned at 2.6-2.7 TB/s.
// Constant across all: in-flight bytes/CU ~ 0.5-1KB (occupancy x MLP trade
// against each other through the VGPR file -- R5 raised MLP, occ fell;
// R6 raised occ, compiler held MLP at 2). Little's law @ ~650cy mixed
// L3/HBM latency: 2.7 TB/s = 11 B/cy/CU needs ~7KB in flight (= where we
// sit); 6 TB/s needs ~17KB/CU -- unreachable via registers (33 loads/wave
// = 132 VGPR payload = R5's occupancy collapse).
// R7: decouple MLP from VGPRs -> global_load_lds (width 16) deep ring.
// 512 blocks x 4 waves; each wave owns a PRIVATE 16KB LDS slice (8-deep
// ring x [1KB p + 1KB t]); ZERO barriers (wave-private LDS, vmcnt is
// per-wave); counted vmcnt(14) steady-state (T3/T4, m218 mechanism),
// drain 12,10,...,0 only in epilogue. In-flight: 14KB/wave x 8 waves/CU
// = 112KB/CU (15x today).
// Predict: LDS 65536, VGPR~32, occ ~25%, dur -> 45-60us, delivered
// 4.5-6 TB/s, FETCH ~134MB. Unchanged => compiler defeated counted vmcnt
// -> inline-asm buffer_load staging next. Worse => revert.

typedef float v4f __attribute__((ext_vector_type(4)));
typedef int   v4i __attribute__((ext_vector_type(4)));

constexpr int   N_TOTAL   = 33554432;
constexpr int   N_VEC     = N_TOTAL / 4;      // 8388608 float4
constexpr int   THREADS   = 256;
constexpr int   WAVES     = THREADS / 64;     // 4
constexpr int   BLOCKS    = 512;              // 2 blocks/CU (LDS-limited)
constexpr int   GWAVES    = BLOCKS * WAVES;   // 2048
constexpr int   STEPS     = N_VEC / (GWAVES * 64);  // 64
constexpr int   DEPTH     = 8;                // ring depth (buffers/wave)
constexpr float NEG_INV_N = -1.0f / 33554432.0f;

__device__ __forceinline__ void gload_lds16(const void* g, void* l) {
    __builtin_amdgcn_global_load_lds(
        (const __attribute__((address_space(1))) unsigned int*)g,
        (__attribute__((address_space(3))) unsigned int*)l,
        16, 0, 0);
}

__device__ __forceinline__ float term4(v4f p, v4i t) {
    float r = 0.0f;
#pragma unroll
    for (int j = 0; j < 4; ++j) {
        float s = (t[j] == 1) ? p[j] : (1.0f - p[j]);
        float q = 1.0f - s;
        r += __logf(s) * q * q;
    }
    return r;
}

#define WAITVM(N) asm volatile("s_waitcnt vmcnt(" #N ")" ::: "memory")

__global__ __launch_bounds__(THREADS) void focal_partial_kernel(
    const v4f* __restrict__ inp,
    const v4i* __restrict__ tgt,
    float* __restrict__ partials)
{
    // per-wave private ring buffers: no __syncthreads anywhere.
    __shared__ v4f ldsP[WAVES][DEPTH][64];   // 32 KB
    __shared__ v4i ldsT[WAVES][DEPTH][64];   // 32 KB

    const int lane = threadIdx.x & 63;
    const int wave = threadIdx.x >> 6;
    const int gw   = blockIdx.x * WAVES + wave;

    // stage step s into ring slot d: HW writes lds base + lane*16, so pass
    // the wave-uniform base; the GLOBAL address is per-lane.
#define STAGE(d, s) do {                                   \
        const int _v = ((s) * GWAVES + gw) * 64 + lane;    \
        gload_lds16(&inp[_v], &ldsP[wave][(d)][0]);        \
        gload_lds16(&tgt[_v], &ldsT[wave][(d)][0]);        \
    } while (0)

#define COMPUTE(b) do {                                    \
        v4f _p = ldsP[wave][(b)][lane];                    \
        v4i _t = ldsT[wave][(b)][lane];                    \
        acc += term4(_p, _t);                              \
    } while (0)

    // prologue: fill 7 of 8 ring slots (14 loads in flight)
#pragma unroll
    for (int d = 0; d < DEPTH - 1; ++d)
        STAGE(d, d);

    float acc = 0.0f;

    // main loop: issue slot s+7, wait until slot s landed (14 newer loads
    // may remain in flight -- never drain to 0), consume slot s.
    for (int s = 0; s < STEPS - DEPTH + 1; ++s) {   // s = 0..56
        STAGE((s + DEPTH - 1) & (DEPTH - 1), s + DEPTH - 1);
        WAITVM(14);
        COMPUTE(s & (DEPTH - 1));
    }

    // epilogue: drain remaining 7 slots (steps 57..63 -> bufs 1..7)
    WAITVM(12); COMPUTE(1);
    WAITVM(10); COMPUTE(2);
    WAITVM(8);  COMPUTE(3);
    WAITVM(6);  COMPUTE(4);
    WAITVM(4);  COMPUTE(5);
    WAITVM(2);  COMPUTE(6);
    WAITVM(0);  COMPUTE(7);

    // wave-64 shuffle reduction
#pragma unroll
    for (int off = 32; off > 0; off >>= 1)
        acc += __shfl_down(acc, off, 64);

    __shared__ float ws[WAVES];
    if (lane == 0) ws[wave] = acc;
    __syncthreads();

    if (threadIdx.x == 0)
        partials[blockIdx.x] = ws[0] + ws[1] + ws[2] + ws[3];
}

__global__ __launch_bounds__(THREADS) void focal_final_kernel(
    const float* __restrict__ partials,
    float* __restrict__ out)
{
    float acc = 0.0f;
#pragma unroll
    for (int k = 0; k < BLOCKS / THREADS; ++k)
        acc += partials[k * THREADS + threadIdx.x];

#pragma unroll
    for (int off = 32; off > 0; off >>= 1)
        acc += __shfl_down(acc, off, 64);

    __shared__ float ws[THREADS / 64];
    int lane = threadIdx.x & 63;
    int wave = threadIdx.x >> 6;
    if (lane == 0) ws[wave] = acc;
    __syncthreads();

    if (threadIdx.x == 0)
        out[0] = (ws[0] + ws[1] + ws[2] + ws[3]) * NEG_INV_N;
}

extern "C" void kernel_launch(void* const* d_in, const int* in_sizes, int n_in,
                              void* d_out, int out_size, void* d_ws, size_t ws_size,
                              hipStream_t stream) {
    const v4f* inp = (const v4f*)d_in[0];
    const v4i* tgt = (const v4i*)d_in[1];
    float*     out = (float*)d_out;
    float*     partials = (float*)d_ws;   // 2 KB scratch

    focal_partial_kernel<<<BLOCKS, THREADS, 0, stream>>>(inp, tgt, partials);
    focal_final_kernel<<<1, THREADS, 0, stream>>>(partials, out);
}

// Round 5
// 261.517 us; speedup vs baseline: 1.0492x; 1.0492x over previous
//
#include <hip/hip_runtime.h>

// Focal loss (gamma=2, w0=w1=1) mean over N=2^25: -mean(log(s)*(1-s)^2),
// s = t ? p : 1-p. Two-stage reduction (no atomics).
//
// R7 post-mortem: LDS ring with GUARANTEED 14 KB/wave in flight (112 KB/CU,
// counted vmcnt, zero barriers) = NULL. Delivered BW pinned at 2.6-2.7 TB/s
// across FOUR structures (VGPR 16-88, occ 22-71%, reg vs LDS, contiguous vs
// grid-stride). Backpressure total (implied queue latency ~10k cy). Cap is
// downstream of all scheduling.
// FETCH_SIZE = 134 MB = EXACTLY one stream. Two hypotheses:
//  H-A: ~50% L3 hit (random-replacement equilibrium on 268MB scan over
//       256MB cache solves to h~0.6 -- plausible); 1.34 TB/s HBM + 1.34
//       L3, and the split or a shared return path is the cap.
//  H-B: gfx94x-formula FETCH undercounts 2x (128B EA reqs); all-HBM at
//       2.68 TB/s = 42% of achievable.
// R8: asymmetric cache biasing = discriminator AND exploit. nt on the
// TARGET stream only (no-allocate) -> p stream (134MB) gets the 256MB L3
// to itself -> ~100% residency; t streams pure HBM. If L3-hit and HBM
// paths serve in parallel: time -> max(134/HBM_read, 134/L3BW) ~ 45-60us.
// Readout: dur 55-75us & FETCH~134MB => H-A+parallel paths. dur ~100us &
// FETCH~268MB => shared-path ceiling (structural). dur & FETCH unchanged
// => ambiguous (H-B or nt not reaching LLC) -> probable roofline next.

typedef float v4f __attribute__((ext_vector_type(4)));
typedef int   v4i __attribute__((ext_vector_type(4)));

constexpr int   N_TOTAL   = 33554432;
constexpr int   N_VEC     = N_TOTAL / 4;          // 8388608 float4
constexpr int   THREADS   = 256;
constexpr int   BLOCKS    = 2048;
constexpr int   GTHREADS  = BLOCKS * THREADS;     // 524288
constexpr int   STEPS     = N_VEC / GTHREADS;     // 16
constexpr float NEG_INV_N = -1.0f / 33554432.0f;

__device__ __forceinline__ float term4(v4f p, v4i t) {
    float r = 0.0f;
#pragma unroll
    for (int j = 0; j < 4; ++j) {
        float s = (t[j] == 1) ? p[j] : (1.0f - p[j]);
        float q = 1.0f - s;
        r += __logf(s) * q * q;
    }
    return r;
}

__global__ __launch_bounds__(THREADS) void focal_partial_kernel(
    const v4f* __restrict__ inp,
    const v4i* __restrict__ tgt,
    float* __restrict__ partials)
{
    const int gtid = blockIdx.x * THREADS + threadIdx.x;

    float acc = 0.0f;
#pragma unroll
    for (int k = 0; k < STEPS; ++k) {
        const int idx = gtid + k * GTHREADS;     // grid-phase coherent sweep
        v4f p = inp[idx];                        // cacheable: bias L3 to p
        v4i t = __builtin_nontemporal_load(&tgt[idx]);  // nt: stream from HBM
        acc += term4(p, t);
    }

    // wave-64 shuffle reduction
#pragma unroll
    for (int off = 32; off > 0; off >>= 1)
        acc += __shfl_down(acc, off, 64);

    __shared__ float ws[THREADS / 64];
    int lane = threadIdx.x & 63;
    int wave = threadIdx.x >> 6;
    if (lane == 0) ws[wave] = acc;
    __syncthreads();

    if (threadIdx.x == 0)
        partials[blockIdx.x] = ws[0] + ws[1] + ws[2] + ws[3];
}

__global__ __launch_bounds__(THREADS) void focal_final_kernel(
    const float* __restrict__ partials,
    float* __restrict__ out)
{
    float acc = 0.0f;
#pragma unroll
    for (int k = 0; k < BLOCKS / THREADS; ++k)
        acc += partials[k * THREADS + threadIdx.x];

#pragma unroll
    for (int off = 32; off > 0; off >>= 1)
        acc += __shfl_down(acc, off, 64);

    __shared__ float ws[THREADS / 64];
    int lane = threadIdx.x & 63;
    int wave = threadIdx.x >> 6;
    if (lane == 0) ws[wave] = acc;
    __syncthreads();

    if (threadIdx.x == 0)
        out[0] = (ws[0] + ws[1] + ws[2] + ws[3]) * NEG_INV_N;
}

extern "C" void kernel_launch(void* const* d_in, const int* in_sizes, int n_in,
                              void* d_out, int out_size, void* d_ws, size_t ws_size,
                              hipStream_t stream) {
    const v4f* inp = (const v4f*)d_in[0];
    const v4i* tgt = (const v4i*)d_in[1];
    float*     out = (float*)d_out;
    float*     partials = (float*)d_ws;   // 8 KB scratch

    focal_partial_kernel<<<BLOCKS, THREADS, 0, stream>>>(inp, tgt, partials);
    focal_final_kernel<<<1, THREADS, 0, stream>>>(partials, out);
}

// Round 6
// 250.760 us; speedup vs baseline: 1.0942x; 1.0429x over previous
//
#include <hip/hip_runtime.h>

// Focal loss (gamma=2, w0=w1=1) mean over N=2^25: -mean(log(s)*(1-s)^2),
// s = t ? p : 1-p. Two-stage reduction (no atomics).
//
// R8 post-mortem: nt-on-target WORKED -- partial kernel fell out of top-5
// (< 76.7us, was 99.5), e2e 273.7 -> 261.5. Bonus facts from the profile:
// harness fills sustain 6.9 TB/s HBM WRITES (HBM is fine; old 2.7 TB/s cap
// was upstream), and e2e = ~156us fixed fills + our kernels + launches, so
// e2e tracks kernel time even when top-5 hides it.
// Revised theory: the poison was L3 allocation churn + mixed hit/miss
// return traffic (268MB/iter allocated into a 256MB L3). R8 removed half
// the churn. R9 removes the rest: ALL-nt (this exact config never ran --
// R0/R3 died on infra). 268MB pure HBM stream @ ~6.3-6.9 TB/s => partial
// ~40-55us.
// Pre-committed readout: e2e 225-245 => churn theory confirmed (fuse final
// kernel next). e2e 255-265 => neutral -> split-fraction biasing next.
// e2e >270 => p's L3 hits were load-bearing -> revert to R8.

typedef float v4f __attribute__((ext_vector_type(4)));
typedef int   v4i __attribute__((ext_vector_type(4)));

constexpr int   N_TOTAL   = 33554432;
constexpr int   N_VEC     = N_TOTAL / 4;          // 8388608 float4
constexpr int   THREADS   = 256;
constexpr int   BLOCKS    = 2048;
constexpr int   GTHREADS  = BLOCKS * THREADS;     // 524288
constexpr int   STEPS     = N_VEC / GTHREADS;     // 16
constexpr float NEG_INV_N = -1.0f / 33554432.0f;

__device__ __forceinline__ float term4(v4f p, v4i t) {
    float r = 0.0f;
#pragma unroll
    for (int j = 0; j < 4; ++j) {
        float s = (t[j] == 1) ? p[j] : (1.0f - p[j]);
        float q = 1.0f - s;
        r += __logf(s) * q * q;
    }
    return r;
}

__global__ __launch_bounds__(THREADS) void focal_partial_kernel(
    const v4f* __restrict__ inp,
    const v4i* __restrict__ tgt,
    float* __restrict__ partials)
{
    const int gtid = blockIdx.x * THREADS + threadIdx.x;

    float acc = 0.0f;
#pragma unroll
    for (int k = 0; k < STEPS; ++k) {
        const int idx = gtid + k * GTHREADS;     // grid-phase coherent sweep
        v4f p = __builtin_nontemporal_load(&inp[idx]);  // nt: no L3 churn
        v4i t = __builtin_nontemporal_load(&tgt[idx]);  // nt: no L3 churn
        acc += term4(p, t);
    }

    // wave-64 shuffle reduction
#pragma unroll
    for (int off = 32; off > 0; off >>= 1)
        acc += __shfl_down(acc, off, 64);

    __shared__ float ws[THREADS / 64];
    int lane = threadIdx.x & 63;
    int wave = threadIdx.x >> 6;
    if (lane == 0) ws[wave] = acc;
    __syncthreads();

    if (threadIdx.x == 0)
        partials[blockIdx.x] = ws[0] + ws[1] + ws[2] + ws[3];
}

__global__ __launch_bounds__(THREADS) void focal_final_kernel(
    const float* __restrict__ partials,
    float* __restrict__ out)
{
    float acc = 0.0f;
#pragma unroll
    for (int k = 0; k < BLOCKS / THREADS; ++k)
        acc += partials[k * THREADS + threadIdx.x];

#pragma unroll
    for (int off = 32; off > 0; off >>= 1)
        acc += __shfl_down(acc, off, 64);

    __shared__ float ws[THREADS / 64];
    int lane = threadIdx.x & 63;
    int wave = threadIdx.x >> 6;
    if (lane == 0) ws[wave] = acc;
    __syncthreads();

    if (threadIdx.x == 0)
        out[0] = (ws[0] + ws[1] + ws[2] + ws[3]) * NEG_INV_N;
}

extern "C" void kernel_launch(void* const* d_in, const int* in_sizes, int n_in,
                              void* d_out, int out_size, void* d_ws, size_t ws_size,
                              hipStream_t stream) {
    const v4f* inp = (const v4f*)d_in[0];
    const v4i* tgt = (const v4i*)d_in[1];
    float*     out = (float*)d_out;
    float*     partials = (float*)d_ws;   // 8 KB scratch

    focal_partial_kernel<<<BLOCKS, THREADS, 0, stream>>>(inp, tgt, partials);
    focal_final_kernel<<<1, THREADS, 0, stream>>>(partials, out);
}